// Round 15
// baseline (297.598 us; speedup 1.0000x reference)
//
#include <hip/hip_runtime.h>
#include <stdint.h>

typedef unsigned short u16;
typedef __attribute__((ext_vector_type(8))) short short8;
typedef __attribute__((ext_vector_type(4))) float f32x4;
typedef __attribute__((ext_vector_type(16))) float f32x16;

typedef __attribute__((address_space(1))) void as1_void;
typedef __attribute__((address_space(3))) void as3_void;

__device__ inline u16 f2bf(float x) {
  uint32_t u = __float_as_uint(x);
  return (u16)((u + 0x7fffu + ((u >> 16) & 1u)) >> 16);
}

__device__ inline void gload16(const void* g, void* l) {
  __builtin_amdgcn_global_load_lds((as1_void*)g, (as3_void*)l, 16, 0, 0);
}

__device__ inline uint32_t cvtpk(float lo, float hi) {
  uint32_t d;
  asm("v_cvt_pk_bf16_f32 %0, %1, %2" : "=v"(d) : "v"(lo), "v"(hi));
  return d;
}

// NOTE: only safe when a and b hold DIFFERENT values (distinct registers).
// Never call with two copies of the same value — regalloc may coalesce them
// into one VGPR and the swap becomes a self-swap (R3/R4/R8 failure cause).
__device__ inline void plswap(uint32_t& a, uint32_t& b) {
  asm("v_permlane32_swap_b32 %0, %1" : "+v"(a), "+v"(b));
}

__device__ inline float fexp2(float x) {
  float r;
  asm("v_exp_f32 %0, %1" : "=v"(r) : "v"(x));
  return r;
}

// device-coherent (cross-XCD-safe) payload accessors
__device__ inline void coh_store(float* p, float v) {
  __hip_atomic_store(p, v, __ATOMIC_RELAXED, __HIP_MEMORY_SCOPE_AGENT);
}
__device__ inline float coh_load(const float* p) {
  return __hip_atomic_load(p, __ATOMIC_RELAXED, __HIP_MEMORY_SCOPE_AGENT);
}

// ---------------- merged f32 -> bf16 conversions (q, kv, 4 weights) ---------
// grid 9217: last block zeroes the attn pair-counters for this launch.
__global__ __launch_bounds__(256) void cvt_all(const float* __restrict__ q,
                                               const float* __restrict__ kv,
                                               const float* __restrict__ Wq,
                                               const float* __restrict__ Wk,
                                               const float* __restrict__ Wv,
                                               const float* __restrict__ Wo,
                                               u16* __restrict__ qb,
                                               u16* __restrict__ kvb,
                                               u16* __restrict__ wall,
                                               int* __restrict__ cnt) {
  const int bx = blockIdx.x;
  if (bx >= 9216) {
    cnt[threadIdx.x] = 0;
    cnt[256 + threadIdx.x] = 0;
    return;
  }
  const float* in;
  u16* out;
  int i;
  if (bx < 4096) {
    in = q; out = qb; i = bx * 256 + threadIdx.x;
  } else if (bx < 8192) {
    in = kv; out = kvb; i = (bx - 4096) * 256 + threadIdx.x;
  } else {
    int widx = (bx - 8192) >> 8;
    in = (widx == 0) ? Wq : (widx == 1) ? Wk : (widx == 2) ? Wv : Wo;
    out = wall + (size_t)widx * 262144;
    i = ((bx - 8192) & 255) * 256 + threadIdx.x;
  }
  float4 v = ((const float4*)in)[i];
  ushort4 o;
  o.x = f2bf(v.x); o.y = f2bf(v.y); o.z = f2bf(v.z); o.w = f2bf(v.w);
  ((ushort4*)out)[i] = o;
}

// ---------------- fused QKV projection GEMM, BK=64 double-buffered (R12) ----
__global__ __launch_bounds__(256) void gemm_qkv(const u16* __restrict__ qb,
                                                const u16* __restrict__ kvb,
                                                const u16* __restrict__ wq,
                                                const u16* __restrict__ wk,
                                                const u16* __restrict__ wv,
                                                const float* __restrict__ bq,
                                                const float* __restrict__ bk,
                                                const float* __restrict__ bv,
                                                u16* __restrict__ Qh,
                                                u16* __restrict__ Kh,
                                                u16* __restrict__ Vt, float qscale) {
  __shared__ __align__(16) char smem[49152];
  const int z = blockIdx.z;
  const u16* A = (z == 0) ? qb : kvb;
  const u16* W = (z == 0) ? wq : (z == 1) ? wk : wv;
  const float* bias = (z == 0) ? bq : (z == 1) ? bk : bv;
  const float prescale = (z == 0) ? qscale : 1.0f;
  u16* Cout = (z == 0) ? Qh : (z == 1) ? Kh : Vt;

  const int tid = threadIdx.x;
  const int lane = tid & 63;
  const int wv_ = tid >> 6;
  const int c = lane & 15;
  const int g = lane >> 4;
  const int wr = wv_ >> 1, wc = wv_ & 1;
  const int m0 = blockIdx.x * 64;
  const int n0 = blockIdx.y * 128;

  const int r0 = tid >> 3, cc = tid & 7;
  const int u0 = cc ^ (r0 & 7);
  const u16* srcA0 = A + (size_t)(m0 + r0) * 512 + u0 * 8;
  const u16* srcW0 = W + (size_t)(n0 + r0) * 512 + u0 * 8;

#define GEMM_STAGE(BUF, KK)                              \
  {                                                      \
    char* ab_ = (char*)smem + (BUF)*24576 + wv_ * 1024;  \
    gload16(srcA0 + (KK), ab_);                          \
    gload16(srcA0 + (KK) + 16384, ab_ + 4096);           \
    gload16(srcW0 + (KK), ab_ + 8192);                   \
    gload16(srcW0 + (KK) + 16384, ab_ + 12288);          \
    gload16(srcW0 + (KK) + 32768, ab_ + 16384);          \
    gload16(srcW0 + (KK) + 49152, ab_ + 20480);          \
  }

  f32x4 acc[2][4];
#pragma unroll
  for (int i = 0; i < 2; i++)
#pragma unroll
    for (int j = 0; j < 4; j++) acc[i][j] = (f32x4){0.f, 0.f, 0.f, 0.f};

  GEMM_STAGE(0, 0)
  __syncthreads();
  int cur = 0;
  const int swa = c & 7;
  for (int it = 0; it < 8; ++it) {
    if (it < 7) GEMM_STAGE(cur ^ 1, (it + 1) * 64)
    const u16* Ab = (const u16*)((char*)smem + cur * 24576);
    const u16* Wb = Ab + 4096;
#pragma unroll
    for (int kd = 0; kd < 2; kd++) {
      short8 af[2], wf[4];
#pragma unroll
      for (int ai = 0; ai < 2; ai++)
        af[ai] = *(const short8*)&Ab[(wr * 32 + ai * 16 + c) * 64 + (((kd * 4 + g) ^ swa) << 3)];
#pragma unroll
      for (int bj = 0; bj < 4; bj++)
        wf[bj] = *(const short8*)&Wb[(wc * 64 + bj * 16 + c) * 64 + (((kd * 4 + g) ^ swa) << 3)];
#pragma unroll
      for (int ai = 0; ai < 2; ai++)
#pragma unroll
        for (int bj = 0; bj < 4; bj++)
          acc[ai][bj] = __builtin_amdgcn_mfma_f32_16x16x32_bf16(af[ai], wf[bj], acc[ai][bj], 0, 0, 0);
    }
    __syncthreads();
    cur ^= 1;
  }

#pragma unroll
  for (int ai = 0; ai < 2; ai++)
#pragma unroll
    for (int bj = 0; bj < 4; bj++)
#pragma unroll
      for (int r = 0; r < 4; r++) {
        int m = m0 + wr * 32 + ai * 16 + g * 4 + r;
        int n = n0 + wc * 64 + bj * 16 + c;
        float v = (acc[ai][bj][r] + bias[n]) * prescale;
        int b = m >> 12, s = m & 4095;
        int h = n >> 6, d = n & 63;
        size_t idx;
        if (z < 2)
          idx = ((size_t)(b * 8 + h) * 4096 + s) * 64 + d;
        else
          idx = ((size_t)(b * 8 + h) * 64 + d) * 4096 + s;
        Cout[idx] = f2bf(v);
      }
}

// ---------------- output projection GEMM, BK=64 dbuf (f32 out, R12) ---------
__global__ __launch_bounds__(256) void gemm_out(const u16* __restrict__ A,
                                                const u16* __restrict__ W,
                                                const float* __restrict__ bias,
                                                float* __restrict__ Cout) {
  __shared__ __align__(16) char smem[49152];
  const int tid = threadIdx.x;
  const int lane = tid & 63;
  const int wv_ = tid >> 6;
  const int c = lane & 15;
  const int g = lane >> 4;
  const int wr = wv_ >> 1, wc = wv_ & 1;
  const int m0 = blockIdx.x * 64;
  const int n0 = blockIdx.y * 128;

  const int r0 = tid >> 3, cc = tid & 7;
  const int u0 = cc ^ (r0 & 7);
  const u16* srcA0 = A + (size_t)(m0 + r0) * 512 + u0 * 8;
  const u16* srcW0 = W + (size_t)(n0 + r0) * 512 + u0 * 8;

  f32x4 acc[2][4];
#pragma unroll
  for (int i = 0; i < 2; i++)
#pragma unroll
    for (int j = 0; j < 4; j++) acc[i][j] = (f32x4){0.f, 0.f, 0.f, 0.f};

  GEMM_STAGE(0, 0)
  __syncthreads();
  int cur = 0;
  const int swa = c & 7;
  for (int it = 0; it < 8; ++it) {
    if (it < 7) GEMM_STAGE(cur ^ 1, (it + 1) * 64)
    const u16* Ab = (const u16*)((char*)smem + cur * 24576);
    const u16* Wb = Ab + 4096;
#pragma unroll
    for (int kd = 0; kd < 2; kd++) {
      short8 af[2], wf[4];
#pragma unroll
      for (int ai = 0; ai < 2; ai++)
        af[ai] = *(const short8*)&Ab[(wr * 32 + ai * 16 + c) * 64 + (((kd * 4 + g) ^ swa) << 3)];
#pragma unroll
      for (int bj = 0; bj < 4; bj++)
        wf[bj] = *(const short8*)&Wb[(wc * 64 + bj * 16 + c) * 64 + (((kd * 4 + g) ^ swa) << 3)];
#pragma unroll
      for (int ai = 0; ai < 2; ai++)
#pragma unroll
        for (int bj = 0; bj < 4; bj++)
          acc[ai][bj] = __builtin_amdgcn_mfma_f32_16x16x32_bf16(af[ai], wf[bj], acc[ai][bj], 0, 0, 0);
    }
    __syncthreads();
    cur ^= 1;
  }

#pragma unroll
  for (int ai = 0; ai < 2; ai++)
#pragma unroll
    for (int bj = 0; bj < 4; bj++)
#pragma unroll
      for (int r = 0; r < 4; r++) {
        int m = m0 + wr * 32 + ai * 16 + g * 4 + r;
        int n = n0 + wc * 64 + bj * 16 + c;
        Cout[(size_t)m * 512 + n] = acc[ai][bj][r] + bias[n];
      }
}

// ---------------- Flash attention: R11 core + last-block combine ------------
// Grid 1024 (XCD-swizzled) = 16 bh x 32 qt x 2 halves. Block 256 thr = 4 waves.
// Core loop identical to R11/R12. Tail: payload written with device-scope
// stores, release fence, atomicAdd pair counter; second-arriving block
// acquires, reads peer payload, combines (pure f32 add, m=0 -> exact),
// stages bf16 tile in LDS, writes aO coalesced (64 B/thread — R13/R14 bug
// was copying only 32 B of each 64 B piece).
__global__ __launch_bounds__(256) void attn_split(const u16* __restrict__ Qh,
                                                  const u16* __restrict__ Kh,
                                                  const u16* __restrict__ Vt,
                                                  float* __restrict__ Op,
                                                  float* __restrict__ Lw,
                                                  int* __restrict__ cnt,
                                                  u16* __restrict__ aO) {
  __shared__ __align__(16) char smem[32768];
  __shared__ int oldv;
  const int tid = threadIdx.x;
  const int lane = tid & 63;
  const int w = tid >> 6;
  const int c5 = lane & 31;
  const int h = lane >> 5;
  const int bid = (blockIdx.x & 7) * 128 + (blockIdx.x >> 3);  // bijective XCD swizzle
  const int half = bid & 1;
  const int qt = (bid >> 1) & 31;
  const int bh = bid >> 6;
  const int q0 = qt * 128 + w * 32;
  const u16* Qb = Qh + (size_t)bh * 262144;
  const u16* Kb = Kh + (size_t)bh * 262144 + (size_t)half * 2048 * 64;
  const u16* Vb = Vt + (size_t)bh * 262144 + half * 2048;

  // Q B-frag (pre-scaled by log2e/8 in projection)
  short8 qf[4];
#pragma unroll
  for (int kd = 0; kd < 4; kd++)
    qf[kd] = *(const short8*)(Qb + (size_t)(q0 + c5) * 64 + kd * 16 + h * 8);

  f32x16 accO[2];
#pragma unroll
  for (int i = 0; i < 16; i++) { accO[0][i] = 0.f; accO[1][i] = 0.f; }
  float l_r = 0.f;

  // gload_lds sources (verified R10): thread t -> LDS row r=t>>4 pos p=t&15
  const int r = tid >> 4, p = tid & 15;
  const int x = p ^ r;
  const int gb = x >> 3, ge = x & 7;
  const u16* srcKA = Kb + (size_t)(r + 32 * gb) * 64 + ge * 8;
  const u16* srcKB = Kb + (size_t)(16 + r + 32 * gb) * 64 + ge * 8;
  const u16* srcVA = Vb + (size_t)(r + 32 * gb) * 4096 + ge * 8;
  const u16* srcVB = Vb + (size_t)(16 + r + 32 * gb) * 4096 + ge * 8;

#define ATTN_STAGE(BUF, T)                                \
  {                                                       \
    char* b_ = (char*)smem + (BUF)*16384 + w * 1024;      \
    gload16(srcKA + (size_t)(T)*4096, b_);                \
    gload16(srcKB + (size_t)(T)*4096, b_ + 4096);         \
    gload16(srcVA + (T)*64, b_ + 8192);                   \
    gload16(srcVB + (T)*64, b_ + 12288);                  \
  }

  ATTN_STAGE(0, 0)
  __syncthreads();
  const int swz = c5 & 15;
  const int rowb = c5 * 128;

  short8 pa_prev[4];   // P-frags of tile t-1 (carried)
  short8 vf_prev[8];   // V-frags of tile t-1 (carried)

  for (int t = 0; t < 32; ++t) {
    const int cur = t & 1;
    if (t < 31) ATTN_STAGE(cur ^ 1, t + 1)

    const u16* Kl = (const u16*)(smem + cur * 16384);
    const u16* Vl = Kl + 4096;

    // ---- MFMA cluster: QK_t then PV_{t-1} (fills matrix pipe) ----
    f32x16 s0, s1;
#pragma unroll
    for (int i = 0; i < 16; i++) { s0[i] = 0.f; s1[i] = 0.f; }
    __builtin_amdgcn_s_setprio(1);
#pragma unroll
    for (int kd = 0; kd < 4; kd++) {
      short8 kf0 = *(const short8*)&Kl[rowb + ((((kd << 1) + h) ^ swz) << 3)];
      short8 kf1 = *(const short8*)&Kl[rowb + (((8 + (kd << 1) + h) ^ swz) << 3)];
      s0 = __builtin_amdgcn_mfma_f32_32x32x16_bf16(kf0, qf[kd], s0, 0, 0, 0);
      s1 = __builtin_amdgcn_mfma_f32_32x32x16_bf16(kf1, qf[kd], s1, 0, 0, 0);
    }
    if (t > 0) {
#pragma unroll
      for (int km = 0; km < 4; km++) {
        accO[0] = __builtin_amdgcn_mfma_f32_32x32x16_bf16(vf_prev[2 * km], pa_prev[km], accO[0], 0, 0, 0);
        accO[1] = __builtin_amdgcn_mfma_f32_32x32x16_bf16(vf_prev[2 * km + 1], pa_prev[km], accO[1], 0, 0, 0);
      }
    }
    __builtin_amdgcn_s_setprio(0);
    __builtin_amdgcn_sched_barrier(0);  // pin: MFMAs issue before softmax VALU

    // ---- softmax_t in the MFMA shadow ----
#pragma unroll
    for (int i = 0; i < 16; i++) { s0[i] = fexp2(s0[i]); s1[i] = fexp2(s1[i]); }

    float tsum0 = ((s0[0] + s1[0]) + (s0[4] + s1[4])) + ((s0[8] + s1[8]) + (s0[12] + s1[12]));
    float tsum1 = ((s0[1] + s1[1]) + (s0[5] + s1[5])) + ((s0[9] + s1[9]) + (s0[13] + s1[13]));
    float tsum2 = ((s0[2] + s1[2]) + (s0[6] + s1[6])) + ((s0[10] + s1[10]) + (s0[14] + s1[14]));
    float tsum3 = ((s0[3] + s1[3]) + (s0[7] + s1[7])) + ((s0[11] + s1[11]) + (s0[15] + s1[15]));
    float rsq = (tsum0 + tsum1) + (tsum2 + tsum3);
    l_r += rsq + __shfl_xor(rsq, 32);

    uint32_t pk0[4][2], pk1[4][2];
#pragma unroll
    for (int u = 0; u < 4; u++) {
      pk0[u][0] = cvtpk(s0[4 * u], s0[4 * u + 1]);
      pk0[u][1] = cvtpk(s0[4 * u + 2], s0[4 * u + 3]);
      pk1[u][0] = cvtpk(s1[4 * u], s1[4 * u + 1]);
      pk1[u][1] = cvtpk(s1[4 * u + 2], s1[4 * u + 3]);
    }
#pragma unroll
    for (int km = 0; km < 2; km++) {
      const int uA = (km & 1) * 2, uB = uA + 1;
      uint32_t a0 = pk0[uA][0], b0 = pk0[uB][0]; plswap(a0, b0);
      uint32_t a1 = pk0[uA][1], b1 = pk0[uB][1]; plswap(a1, b1);
      union { uint32_t u[4]; short8 s; } uu;
      uu.u[0] = a0; uu.u[1] = a1; uu.u[2] = b0; uu.u[3] = b1;
      pa_prev[km] = uu.s;
    }
#pragma unroll
    for (int km = 2; km < 4; km++) {
      const int uA = (km & 1) * 2, uB = uA + 1;
      uint32_t a0 = pk1[uA][0], b0 = pk1[uB][0]; plswap(a0, b0);
      uint32_t a1 = pk1[uA][1], b1 = pk1[uB][1]; plswap(a1, b1);
      union { uint32_t u[4]; short8 s; } uu;
      uu.u[0] = a0; uu.u[1] = a1; uu.u[2] = b0; uu.u[3] = b1;
      pa_prev[km] = uu.s;
    }

    // ---- V_t frags LDS -> regs (consumed by PV at iter t+1) ----
#pragma unroll
    for (int km = 0; km < 4; km++) {
      vf_prev[2 * km]     = *(const short8*)&Vl[rowb + ((((km << 1) + h) ^ swz) << 3)];
      vf_prev[2 * km + 1] = *(const short8*)&Vl[rowb + (((8 + (km << 1) + h) ^ swz) << 3)];
    }

    __syncthreads();  // drains DMA; flips buffer
  }

  // ---- epilogue: PV_31 ----
#pragma unroll
  for (int km = 0; km < 4; km++) {
    accO[0] = __builtin_amdgcn_mfma_f32_32x32x16_bf16(vf_prev[2 * km], pa_prev[km], accO[0], 0, 0, 0);
    accO[1] = __builtin_amdgcn_mfma_f32_32x32x16_bf16(vf_prev[2 * km + 1], pa_prev[km], accO[1], 0, 0, 0);
  }

  // ---- publish f32 partials + l with device-scope (cross-XCD-safe) stores --
  const size_t pbase = (size_t)(half * 16 + bh) * 4096 + q0 + c5;
  float* Opw = Op + pbase * 64;
#pragma unroll
  for (int db = 0; db < 2; db++)
#pragma unroll
    for (int rr = 0; rr < 16; rr++) {
      int d = db * 32 + 4 * h + (rr & 3) + 8 * (rr >> 2);
      coh_store(&Opw[d], accO[db][rr]);
    }
  if (h == 0) coh_store(&Lw[pbase], l_r);

  __threadfence();       // release ordering
  __syncthreads();
  if (tid == 0) oldv = atomicAdd(&cnt[(bh << 5) + qt], 1);
  __syncthreads();
  if (oldv != 1) return;  // first block of the pair is done
  __threadfence();        // acquire ordering

  // ---- combine: local accO + peer partials -> bf16 tile in LDS ----
  const size_t obase = (size_t)((half ^ 1) * 16 + bh) * 4096 + q0 + c5;
  const float* Os = Op + obase * 64;
  const float inv = 1.f / (l_r + coh_load(&Lw[obase]));
  u16* tile = (u16*)smem;  // [128][64]
#pragma unroll
  for (int db = 0; db < 2; db++)
#pragma unroll
    for (int rr = 0; rr < 16; rr++) {
      int d = db * 32 + 4 * h + (rr & 3) + 8 * (rr >> 2);
      tile[(w * 32 + c5) * 64 + d] = f2bf((accO[db][rr] + coh_load(&Os[d])) * inv);
    }
  __syncthreads();
  // coalesced write: 128 rows x 128B; thread t -> row t>>1, 64B piece t&1
  {
    const int row = tid >> 1, hf = tid & 1;
    const int b = bh >> 3, hh = bh & 7;
    u16* dst = aO + ((size_t)(b * 4096 + qt * 128 + row)) * 512 + hh * 64 + hf * 32;
    const u16* src = tile + row * 64 + hf * 32;
    ((int4*)dst)[0] = ((const int4*)src)[0];
    ((int4*)dst)[1] = ((const int4*)src)[1];
    ((int4*)dst)[2] = ((const int4*)src)[2];
    ((int4*)dst)[3] = ((const int4*)src)[3];
  }
}

// ---------------- host launch ----------------
extern "C" void kernel_launch(void* const* d_in, const int* in_sizes, int n_in,
                              void* d_out, int out_size, void* d_ws, size_t ws_size,
                              hipStream_t stream) {
  const float* q  = (const float*)d_in[0];
  const float* kv = (const float*)d_in[1];
  const float* Wq = (const float*)d_in[2];
  const float* bq = (const float*)d_in[3];
  const float* Wk = (const float*)d_in[4];
  const float* bk = (const float*)d_in[5];
  const float* Wv = (const float*)d_in[6];
  const float* bv = (const float*)d_in[7];
  const float* Wo = (const float*)d_in[8];
  const float* bo = (const float*)d_in[9];

  const size_t MB = 1u << 20;
  char* ws = (char*)d_ws;
  u16* qb  = (u16*)(ws + 0 * MB);
  u16* kvb = (u16*)(ws + 8 * MB);
  u16* wqb = (u16*)(ws + 16 * MB);   // 4 weights contiguous: wq,wk,wv,wo
  u16* wkb = (u16*)(ws + 16 * MB + 524288);
  u16* wvb = (u16*)(ws + 17 * MB);
  u16* wob = (u16*)(ws + 17 * MB + 524288);
  u16* Qh  = (u16*)(ws + 18 * MB);   // [16][4096][64], pre-scaled by log2e/8
  u16* Kh  = (u16*)(ws + 26 * MB);   // [16][4096][64]
  u16* Vt  = (u16*)(ws + 34 * MB);   // [16][64][4096]
  u16* aO  = (u16*)(ws + 42 * MB);   // [8192][512]
  float* Op = (float*)(ws + 50 * MB);  // [2][16][4096][64] f32 partials
  float* Lw = (float*)(ws + 84 * MB);  // [2][16][4096] f32 row sums
  int*   cnt = (int*)(ws + 85 * MB);   // [512] pair counters

  cvt_all<<<dim3(9217), dim3(256), 0, stream>>>(q, kv, Wq, Wk, Wv, Wo, qb, kvb, wqb, cnt);

  const float qscale = 0.125f * 1.44269504088896340736f;  // (1/sqrt(64)) * log2(e)
  gemm_qkv<<<dim3(128, 4, 3), dim3(256), 0, stream>>>(qb, kvb, wqb, wkb, wvb,
                                                      bq, bk, bv, Qh, Kh, Vt, qscale);

  attn_split<<<dim3(1024), dim3(256), 0, stream>>>(Qh, Kh, Vt, Op, Lw, cnt, aO);

  gemm_out<<<dim3(128, 4), dim3(256), 0, stream>>>(aO, wob, bo, (float*)d_out);
}

// Round 16
// 140.117 us; speedup vs baseline: 2.1239x; 2.1239x over previous
//
#include <hip/hip_runtime.h>
#include <stdint.h>

typedef unsigned short u16;
typedef __attribute__((ext_vector_type(8))) short short8;
typedef __attribute__((ext_vector_type(4))) float f32x4;
typedef __attribute__((ext_vector_type(16))) float f32x16;

typedef __attribute__((address_space(1))) void as1_void;
typedef __attribute__((address_space(3))) void as3_void;

__device__ inline u16 f2bf(float x) {
  uint32_t u = __float_as_uint(x);
  return (u16)((u + 0x7fffu + ((u >> 16) & 1u)) >> 16);
}

__device__ inline void gload16(const void* g, void* l) {
  __builtin_amdgcn_global_load_lds((as1_void*)g, (as3_void*)l, 16, 0, 0);
}

__device__ inline uint32_t cvtpk(float lo, float hi) {
  uint32_t d;
  asm("v_cvt_pk_bf16_f32 %0, %1, %2" : "=v"(d) : "v"(lo), "v"(hi));
  return d;
}

// NOTE: only safe when a and b hold DIFFERENT values (distinct registers).
// Never call with two copies of the same value — regalloc may coalesce them
// into one VGPR and the swap becomes a self-swap (R3/R4/R8 failure cause).
__device__ inline void plswap(uint32_t& a, uint32_t& b) {
  asm("v_permlane32_swap_b32 %0, %1" : "+v"(a), "+v"(b));
}

__device__ inline float fexp2(float x) {
  float r;
  asm("v_exp_f32 %0, %1" : "=v"(r) : "v"(x));
  return r;
}

// ---------------- merged f32 -> bf16 conversions (q, kv, 4 weights) ---------
__global__ __launch_bounds__(256) void cvt_all(const float* __restrict__ q,
                                               const float* __restrict__ kv,
                                               const float* __restrict__ Wq,
                                               const float* __restrict__ Wk,
                                               const float* __restrict__ Wv,
                                               const float* __restrict__ Wo,
                                               u16* __restrict__ qb,
                                               u16* __restrict__ kvb,
                                               u16* __restrict__ wall) {
  const int bx = blockIdx.x;
  const float* in;
  u16* out;
  int i;
  if (bx < 4096) {
    in = q; out = qb; i = bx * 256 + threadIdx.x;
  } else if (bx < 8192) {
    in = kv; out = kvb; i = (bx - 4096) * 256 + threadIdx.x;
  } else {
    int widx = (bx - 8192) >> 8;
    in = (widx == 0) ? Wq : (widx == 1) ? Wk : (widx == 2) ? Wv : Wo;
    out = wall + (size_t)widx * 262144;
    i = ((bx - 8192) & 255) * 256 + threadIdx.x;
  }
  float4 v = ((const float4*)in)[i];
  ushort4 o;
  o.x = f2bf(v.x); o.y = f2bf(v.y); o.z = f2bf(v.z); o.w = f2bf(v.w);
  ((ushort4*)out)[i] = o;
}

// ---------------- fused QKV projection GEMM, BK=64 double-buffered (R12) ----
__global__ __launch_bounds__(256) void gemm_qkv(const u16* __restrict__ qb,
                                                const u16* __restrict__ kvb,
                                                const u16* __restrict__ wq,
                                                const u16* __restrict__ wk,
                                                const u16* __restrict__ wv,
                                                const float* __restrict__ bq,
                                                const float* __restrict__ bk,
                                                const float* __restrict__ bv,
                                                u16* __restrict__ Qh,
                                                u16* __restrict__ Kh,
                                                u16* __restrict__ Vt, float qscale) {
  __shared__ __align__(16) char smem[49152];
  const int z = blockIdx.z;
  const u16* A = (z == 0) ? qb : kvb;
  const u16* W = (z == 0) ? wq : (z == 1) ? wk : wv;
  const float* bias = (z == 0) ? bq : (z == 1) ? bk : bv;
  const float prescale = (z == 0) ? qscale : 1.0f;
  u16* Cout = (z == 0) ? Qh : (z == 1) ? Kh : Vt;

  const int tid = threadIdx.x;
  const int lane = tid & 63;
  const int wv_ = tid >> 6;
  const int c = lane & 15;
  const int g = lane >> 4;
  const int wr = wv_ >> 1, wc = wv_ & 1;
  const int m0 = blockIdx.x * 64;
  const int n0 = blockIdx.y * 128;

  const int r0 = tid >> 3, cc = tid & 7;
  const int u0 = cc ^ (r0 & 7);
  const u16* srcA0 = A + (size_t)(m0 + r0) * 512 + u0 * 8;
  const u16* srcW0 = W + (size_t)(n0 + r0) * 512 + u0 * 8;

#define GEMM_STAGE(BUF, KK)                              \
  {                                                      \
    char* ab_ = (char*)smem + (BUF)*24576 + wv_ * 1024;  \
    gload16(srcA0 + (KK), ab_);                          \
    gload16(srcA0 + (KK) + 16384, ab_ + 4096);           \
    gload16(srcW0 + (KK), ab_ + 8192);                   \
    gload16(srcW0 + (KK) + 16384, ab_ + 12288);          \
    gload16(srcW0 + (KK) + 32768, ab_ + 16384);          \
    gload16(srcW0 + (KK) + 49152, ab_ + 20480);          \
  }

  f32x4 acc[2][4];
#pragma unroll
  for (int i = 0; i < 2; i++)
#pragma unroll
    for (int j = 0; j < 4; j++) acc[i][j] = (f32x4){0.f, 0.f, 0.f, 0.f};

  GEMM_STAGE(0, 0)
  __syncthreads();
  int cur = 0;
  const int swa = c & 7;
  for (int it = 0; it < 8; ++it) {
    if (it < 7) GEMM_STAGE(cur ^ 1, (it + 1) * 64)
    const u16* Ab = (const u16*)((char*)smem + cur * 24576);
    const u16* Wb = Ab + 4096;
#pragma unroll
    for (int kd = 0; kd < 2; kd++) {
      short8 af[2], wf[4];
#pragma unroll
      for (int ai = 0; ai < 2; ai++)
        af[ai] = *(const short8*)&Ab[(wr * 32 + ai * 16 + c) * 64 + (((kd * 4 + g) ^ swa) << 3)];
#pragma unroll
      for (int bj = 0; bj < 4; bj++)
        wf[bj] = *(const short8*)&Wb[(wc * 64 + bj * 16 + c) * 64 + (((kd * 4 + g) ^ swa) << 3)];
#pragma unroll
      for (int ai = 0; ai < 2; ai++)
#pragma unroll
        for (int bj = 0; bj < 4; bj++)
          acc[ai][bj] = __builtin_amdgcn_mfma_f32_16x16x32_bf16(af[ai], wf[bj], acc[ai][bj], 0, 0, 0);
    }
    __syncthreads();
    cur ^= 1;
  }

#pragma unroll
  for (int ai = 0; ai < 2; ai++)
#pragma unroll
    for (int bj = 0; bj < 4; bj++)
#pragma unroll
      for (int r = 0; r < 4; r++) {
        int m = m0 + wr * 32 + ai * 16 + g * 4 + r;
        int n = n0 + wc * 64 + bj * 16 + c;
        float v = (acc[ai][bj][r] + bias[n]) * prescale;
        int b = m >> 12, s = m & 4095;
        int h = n >> 6, d = n & 63;
        size_t idx;
        if (z < 2)
          idx = ((size_t)(b * 8 + h) * 4096 + s) * 64 + d;
        else
          idx = ((size_t)(b * 8 + h) * 64 + d) * 4096 + s;
        Cout[idx] = f2bf(v);
      }
}

// ---------------- output projection GEMM, BK=64 dbuf (f32 out, R12) ---------
__global__ __launch_bounds__(256) void gemm_out(const u16* __restrict__ A,
                                                const u16* __restrict__ W,
                                                const float* __restrict__ bias,
                                                float* __restrict__ Cout) {
  __shared__ __align__(16) char smem[49152];
  const int tid = threadIdx.x;
  const int lane = tid & 63;
  const int wv_ = tid >> 6;
  const int c = lane & 15;
  const int g = lane >> 4;
  const int wr = wv_ >> 1, wc = wv_ & 1;
  const int m0 = blockIdx.x * 64;
  const int n0 = blockIdx.y * 128;

  const int r0 = tid >> 3, cc = tid & 7;
  const int u0 = cc ^ (r0 & 7);
  const u16* srcA0 = A + (size_t)(m0 + r0) * 512 + u0 * 8;
  const u16* srcW0 = W + (size_t)(n0 + r0) * 512 + u0 * 8;

  f32x4 acc[2][4];
#pragma unroll
  for (int i = 0; i < 2; i++)
#pragma unroll
    for (int j = 0; j < 4; j++) acc[i][j] = (f32x4){0.f, 0.f, 0.f, 0.f};

  GEMM_STAGE(0, 0)
  __syncthreads();
  int cur = 0;
  const int swa = c & 7;
  for (int it = 0; it < 8; ++it) {
    if (it < 7) GEMM_STAGE(cur ^ 1, (it + 1) * 64)
    const u16* Ab = (const u16*)((char*)smem + cur * 24576);
    const u16* Wb = Ab + 4096;
#pragma unroll
    for (int kd = 0; kd < 2; kd++) {
      short8 af[2], wf[4];
#pragma unroll
      for (int ai = 0; ai < 2; ai++)
        af[ai] = *(const short8*)&Ab[(wr * 32 + ai * 16 + c) * 64 + (((kd * 4 + g) ^ swa) << 3)];
#pragma unroll
      for (int bj = 0; bj < 4; bj++)
        wf[bj] = *(const short8*)&Wb[(wc * 64 + bj * 16 + c) * 64 + (((kd * 4 + g) ^ swa) << 3)];
#pragma unroll
      for (int ai = 0; ai < 2; ai++)
#pragma unroll
        for (int bj = 0; bj < 4; bj++)
          acc[ai][bj] = __builtin_amdgcn_mfma_f32_16x16x32_bf16(af[ai], wf[bj], acc[ai][bj], 0, 0, 0);
    }
    __syncthreads();
    cur ^= 1;
  }

#pragma unroll
  for (int ai = 0; ai < 2; ai++)
#pragma unroll
    for (int bj = 0; bj < 4; bj++)
#pragma unroll
      for (int r = 0; r < 4; r++) {
        int m = m0 + wr * 32 + ai * 16 + g * 4 + r;
        int n = n0 + wc * 64 + bj * 16 + c;
        Cout[(size_t)m * 512 + n] = acc[ai][bj][r] + bias[n];
      }
}

// ---------------- Flash attention: PV-lagged software pipeline (R11/R12) ----
// Grid 1024 (XCD-swizzled) = 16 bh x 32 qt x 2 halves. Block 256 thr = 4 waves.
// K/V LDS double-buffered (gload_lds, linear dest + inv-swizzled source).
// Per iteration t: stage t+1 -> dead buffer; QK_t then PV_{t-1} MFMAs
// back-to-back; softmax_t in the MFMA shadow; V_t frags LDS->regs; 1 barrier.
// No-max softmax (p = exp2(s)). Cross-half l-reduce hoisted out of the loop
// (sum is linear; same lane pairing every iteration).
__global__ __launch_bounds__(256) void attn_split(const u16* __restrict__ Qh,
                                                  const u16* __restrict__ Kh,
                                                  const u16* __restrict__ Vt,
                                                  float* __restrict__ Op,
                                                  float* __restrict__ Lw) {
  __shared__ __align__(16) char smem[32768];
  const int tid = threadIdx.x;
  const int lane = tid & 63;
  const int w = tid >> 6;
  const int c5 = lane & 31;
  const int h = lane >> 5;
  const int bid = (blockIdx.x & 7) * 128 + (blockIdx.x >> 3);  // bijective XCD swizzle
  const int half = bid & 1;
  const int qt = (bid >> 1) & 31;
  const int bh = bid >> 6;
  const int q0 = qt * 128 + w * 32;
  const u16* Qb = Qh + (size_t)bh * 262144;
  const u16* Kb = Kh + (size_t)bh * 262144 + (size_t)half * 2048 * 64;
  const u16* Vb = Vt + (size_t)bh * 262144 + half * 2048;

  // Q B-frag (pre-scaled by log2e/8 in projection)
  short8 qf[4];
#pragma unroll
  for (int kd = 0; kd < 4; kd++)
    qf[kd] = *(const short8*)(Qb + (size_t)(q0 + c5) * 64 + kd * 16 + h * 8);

  f32x16 accO[2];
#pragma unroll
  for (int i = 0; i < 16; i++) { accO[0][i] = 0.f; accO[1][i] = 0.f; }
  float l_loc = 0.f;

  // gload_lds sources (verified R10): thread t -> LDS row r=t>>4 pos p=t&15
  const int r = tid >> 4, p = tid & 15;
  const int x = p ^ r;
  const int gb = x >> 3, ge = x & 7;
  const u16* srcKA = Kb + (size_t)(r + 32 * gb) * 64 + ge * 8;
  const u16* srcKB = Kb + (size_t)(16 + r + 32 * gb) * 64 + ge * 8;
  const u16* srcVA = Vb + (size_t)(r + 32 * gb) * 4096 + ge * 8;
  const u16* srcVB = Vb + (size_t)(16 + r + 32 * gb) * 4096 + ge * 8;

#define ATTN_STAGE(BUF, T)                                \
  {                                                       \
    char* b_ = (char*)smem + (BUF)*16384 + w * 1024;      \
    gload16(srcKA + (size_t)(T)*4096, b_);                \
    gload16(srcKB + (size_t)(T)*4096, b_ + 4096);         \
    gload16(srcVA + (T)*64, b_ + 8192);                   \
    gload16(srcVB + (T)*64, b_ + 12288);                  \
  }

  ATTN_STAGE(0, 0)
  __syncthreads();
  const int swz = c5 & 15;
  const int rowb = c5 * 128;

  short8 pa_prev[4];   // P-frags of tile t-1 (carried)
  short8 vf_prev[8];   // V-frags of tile t-1 (carried)

  for (int t = 0; t < 32; ++t) {
    const int cur = t & 1;
    if (t < 31) ATTN_STAGE(cur ^ 1, t + 1)

    const u16* Kl = (const u16*)(smem + cur * 16384);
    const u16* Vl = Kl + 4096;

    // ---- MFMA cluster: QK_t then PV_{t-1} (fills matrix pipe) ----
    f32x16 s0, s1;
#pragma unroll
    for (int i = 0; i < 16; i++) { s0[i] = 0.f; s1[i] = 0.f; }
    __builtin_amdgcn_s_setprio(1);
#pragma unroll
    for (int kd = 0; kd < 4; kd++) {
      short8 kf0 = *(const short8*)&Kl[rowb + ((((kd << 1) + h) ^ swz) << 3)];
      short8 kf1 = *(const short8*)&Kl[rowb + (((8 + (kd << 1) + h) ^ swz) << 3)];
      s0 = __builtin_amdgcn_mfma_f32_32x32x16_bf16(kf0, qf[kd], s0, 0, 0, 0);
      s1 = __builtin_amdgcn_mfma_f32_32x32x16_bf16(kf1, qf[kd], s1, 0, 0, 0);
    }
    if (t > 0) {
#pragma unroll
      for (int km = 0; km < 4; km++) {
        accO[0] = __builtin_amdgcn_mfma_f32_32x32x16_bf16(vf_prev[2 * km], pa_prev[km], accO[0], 0, 0, 0);
        accO[1] = __builtin_amdgcn_mfma_f32_32x32x16_bf16(vf_prev[2 * km + 1], pa_prev[km], accO[1], 0, 0, 0);
      }
    }
    __builtin_amdgcn_s_setprio(0);
    __builtin_amdgcn_sched_barrier(0);  // pin: MFMAs issue before softmax VALU

    // ---- softmax_t in the MFMA shadow ----
#pragma unroll
    for (int i = 0; i < 16; i++) { s0[i] = fexp2(s0[i]); s1[i] = fexp2(s1[i]); }

    float tsum0 = ((s0[0] + s1[0]) + (s0[4] + s1[4])) + ((s0[8] + s1[8]) + (s0[12] + s1[12]));
    float tsum1 = ((s0[1] + s1[1]) + (s0[5] + s1[5])) + ((s0[9] + s1[9]) + (s0[13] + s1[13]));
    float tsum2 = ((s0[2] + s1[2]) + (s0[6] + s1[6])) + ((s0[10] + s1[10]) + (s0[14] + s1[14]));
    float tsum3 = ((s0[3] + s1[3]) + (s0[7] + s1[7])) + ((s0[11] + s1[11]) + (s0[15] + s1[15]));
    l_loc += (tsum0 + tsum1) + (tsum2 + tsum3);

    uint32_t pk0[4][2], pk1[4][2];
#pragma unroll
    for (int u = 0; u < 4; u++) {
      pk0[u][0] = cvtpk(s0[4 * u], s0[4 * u + 1]);
      pk0[u][1] = cvtpk(s0[4 * u + 2], s0[4 * u + 3]);
      pk1[u][0] = cvtpk(s1[4 * u], s1[4 * u + 1]);
      pk1[u][1] = cvtpk(s1[4 * u + 2], s1[4 * u + 3]);
    }
#pragma unroll
    for (int km = 0; km < 2; km++) {
      const int uA = (km & 1) * 2, uB = uA + 1;
      uint32_t a0 = pk0[uA][0], b0 = pk0[uB][0]; plswap(a0, b0);
      uint32_t a1 = pk0[uA][1], b1 = pk0[uB][1]; plswap(a1, b1);
      union { uint32_t u[4]; short8 s; } uu;
      uu.u[0] = a0; uu.u[1] = a1; uu.u[2] = b0; uu.u[3] = b1;
      pa_prev[km] = uu.s;
    }
#pragma unroll
    for (int km = 2; km < 4; km++) {
      const int uA = (km & 1) * 2, uB = uA + 1;
      uint32_t a0 = pk1[uA][0], b0 = pk1[uB][0]; plswap(a0, b0);
      uint32_t a1 = pk1[uA][1], b1 = pk1[uB][1]; plswap(a1, b1);
      union { uint32_t u[4]; short8 s; } uu;
      uu.u[0] = a0; uu.u[1] = a1; uu.u[2] = b0; uu.u[3] = b1;
      pa_prev[km] = uu.s;
    }

    // ---- V_t frags LDS -> regs (consumed by PV at iter t+1) ----
#pragma unroll
    for (int km = 0; km < 4; km++) {
      vf_prev[2 * km]     = *(const short8*)&Vl[rowb + ((((km << 1) + h) ^ swz) << 3)];
      vf_prev[2 * km + 1] = *(const short8*)&Vl[rowb + (((8 + (km << 1) + h) ^ swz) << 3)];
    }

    __syncthreads();  // drains DMA; flips buffer
  }

  // ---- epilogue: PV_31 + deferred cross-half l reduce ----
#pragma unroll
  for (int km = 0; km < 4; km++) {
    accO[0] = __builtin_amdgcn_mfma_f32_32x32x16_bf16(vf_prev[2 * km], pa_prev[km], accO[0], 0, 0, 0);
    accO[1] = __builtin_amdgcn_mfma_f32_32x32x16_bf16(vf_prev[2 * km + 1], pa_prev[km], accO[1], 0, 0, 0);
  }
  const float l_r = l_loc + __shfl_xor(l_loc, 32);

  // ---- write f32 partials + l to workspace ----
  const size_t pbase = (size_t)(half * 16 + bh) * 4096 + q0 + c5;
  float* Opw = Op + pbase * 64;
#pragma unroll
  for (int db = 0; db < 2; db++)
#pragma unroll
    for (int rr = 0; rr < 16; rr++) {
      int d = db * 32 + 4 * h + (rr & 3) + 8 * (rr >> 2);
      Opw[d] = accO[db][rr];
    }
  if (h == 0) Lw[pbase] = l_r;
}

// ---------------- combine: merge 2 KV-half partials, write bf16 aO ----------
__global__ __launch_bounds__(256) void attn_combine(const float* __restrict__ Op,
                                                    const float* __restrict__ Lw,
                                                    u16* __restrict__ aO) {
  int tg = blockIdx.x * 256 + threadIdx.x;
  int bhq = tg >> 3, seg = tg & 7;
  const float* p0 = Op + (size_t)bhq * 64 + seg * 8;
  const float* p1 = p0 + 4194304;  // half-1 base = 16*4096*64
  float inv = 1.f / (Lw[bhq] + Lw[65536 + bhq]);
  float4 x0 = ((const float4*)p0)[0], x1 = ((const float4*)p0)[1];
  float4 y0 = ((const float4*)p1)[0], y1 = ((const float4*)p1)[1];
  ushort4 o0, o1;
  o0.x = f2bf((x0.x + y0.x) * inv);
  o0.y = f2bf((x0.y + y0.y) * inv);
  o0.z = f2bf((x0.z + y0.z) * inv);
  o0.w = f2bf((x0.w + y0.w) * inv);
  o1.x = f2bf((x1.x + y1.x) * inv);
  o1.y = f2bf((x1.y + y1.y) * inv);
  o1.z = f2bf((x1.z + y1.z) * inv);
  o1.w = f2bf((x1.w + y1.w) * inv);
  int bh = bhq >> 12, q = bhq & 4095;
  int b = bh >> 3, hh = bh & 7;
  u16* dst = aO + ((size_t)(b * 4096 + q)) * 512 + hh * 64 + seg * 8;
  ((ushort4*)dst)[0] = o0;
  ((ushort4*)dst)[1] = o1;
}

// ---------------- host launch ----------------
extern "C" void kernel_launch(void* const* d_in, const int* in_sizes, int n_in,
                              void* d_out, int out_size, void* d_ws, size_t ws_size,
                              hipStream_t stream) {
  const float* q  = (const float*)d_in[0];
  const float* kv = (const float*)d_in[1];
  const float* Wq = (const float*)d_in[2];
  const float* bq = (const float*)d_in[3];
  const float* Wk = (const float*)d_in[4];
  const float* bk = (const float*)d_in[5];
  const float* Wv = (const float*)d_in[6];
  const float* bv = (const float*)d_in[7];
  const float* Wo = (const float*)d_in[8];
  const float* bo = (const float*)d_in[9];

  const size_t MB = 1u << 20;
  char* ws = (char*)d_ws;
  u16* qb  = (u16*)(ws + 0 * MB);
  u16* kvb = (u16*)(ws + 8 * MB);
  u16* wqb = (u16*)(ws + 16 * MB);   // 4 weights contiguous: wq,wk,wv,wo
  u16* wkb = (u16*)(ws + 16 * MB + 524288);
  u16* wvb = (u16*)(ws + 17 * MB);
  u16* wob = (u16*)(ws + 17 * MB + 524288);
  u16* Qh  = (u16*)(ws + 18 * MB);   // [16][4096][64], pre-scaled by log2e/8
  u16* Kh  = (u16*)(ws + 26 * MB);   // [16][4096][64]
  u16* Vt  = (u16*)(ws + 34 * MB);   // [16][64][4096]
  u16* aO  = (u16*)(ws + 42 * MB);   // [8192][512]
  float* Op = (float*)(ws + 50 * MB);  // [2][16][4096][64] f32 partials
  float* Lw = (float*)(ws + 84 * MB);  // [2][16][4096] f32 row sums

  cvt_all<<<dim3(9216), dim3(256), 0, stream>>>(q, kv, Wq, Wk, Wv, Wo, qb, kvb, wqb);

  const float qscale = 0.125f * 1.44269504088896340736f;  // (1/sqrt(64)) * log2(e)
  gemm_qkv<<<dim3(128, 4, 3), dim3(256), 0, stream>>>(qb, kvb, wqb, wkb, wvb,
                                                      bq, bk, bv, Qh, Kh, Vt, qscale);

  attn_split<<<dim3(1024), dim3(256), 0, stream>>>(Qh, Kh, Vt, Op, Lw);
  attn_combine<<<dim3(2048), dim3(256), 0, stream>>>(Op, Lw, aO);

  gemm_out<<<dim3(128, 4), dim3(256), 0, stream>>>(aO, wob, bo, (float*)d_out);
}